// Round 5
// baseline (106.369 us; speedup 1.0000x reference)
//
#include <hip/hip_runtime.h>

// ScaledDotProductAttention B=8, L=2048, D=64, fp32 in/out.
//
// Three-launch scheme (ws >= 16 MB):
//  1) prepass: K -> fp16 copy (K16), V -> fp16 transposed (VT16) in d_ws.
//     Q is NOT pre-cast: each Q row is used by exactly one wave (no reuse).
//  2) attn_part: grid 1024 = 8 batch x 64 qblock x 2 ksplit -> 4 blocks/CU,
//     16 waves/CU (R4 had 2 blocks/CU = the latency bottleneck).
//     Block = 32 queries, 4 waves; wave w owns keys [ks*1024 + w*256, +256).
//     B-frags load straight from K16 / VT16 rows (global half8); only P
//     round-trips through wave-private LDS. Q pre-scaled by 0.125*log2(e)
//     so softmax is a single v_exp_f32 (exp2) per score, no mul.
//     Cross-wave (O,l) combine in LDS; block writes UN-normalized partial
//     (O32x64, l32) to ws.
//  3) combine: O = (O0+O1)/(l0+l1), 512 blocks, float4.
// Fallback: proven R3 kernel if ws too small.
//
// batch = blockIdx&7 == XCD id heuristic: each batch's K16+VT16 (1 MB) stays
// hot in its XCD's 4 MB L2.

#define B_ 8
#define L_ 2048
#define D_ 64
#define NT 256
#define PS 40              // P row stride in halves (16B-aligned)
#define TK 32              // keys per inner tile

typedef _Float16 half8_t __attribute__((ext_vector_type(8)));
typedef float f32x4 __attribute__((ext_vector_type(4)));

#define SCALE_LOG2E 0.1803368801111244f   // 0.125 * log2(e)

// ---------------------------------------------------------------- prepass --
// blocks 0..511: K cast; 512..767: V transpose.
__global__ __launch_bounds__(NT) void prepass(
    const float* __restrict__ K, const float* __restrict__ V,
    _Float16* __restrict__ K16, _Float16* __restrict__ VT16)
{
    const int blk = blockIdx.x;
    const int t = threadIdx.x;
    if (blk < 512) {
        const int i = blk * NT + t;                  // half8 index, 131072 total
        const float4* s4 = (const float4*)K;
        const float4 a = s4[2 * i], b = s4[2 * i + 1];
        half8_t w;
        w[0] = (_Float16)a.x; w[1] = (_Float16)a.y;
        w[2] = (_Float16)a.z; w[3] = (_Float16)a.w;
        w[4] = (_Float16)b.x; w[5] = (_Float16)b.y;
        w[6] = (_Float16)b.z; w[7] = (_Float16)b.w;
        ((half8_t*)K16)[i] = w;
    } else {
        __shared__ __align__(16) _Float16 Lt[64 * 72];   // [dim][key] tile
        const int vblk = blk - 512;
        const int bb = vblk >> 5;            // batch
        const int kt = vblk & 31;            // 64-key tile
        const int r  = t >> 2;               // key row 0..63
        const int ch = t & 3;                // 16-dim chunk
        const float* vrow = V + ((size_t)bb * L_ + kt * 64 + r) * D_ + ch * 16;
        #pragma unroll
        for (int i = 0; i < 4; ++i) {
            const float4 f = ((const float4*)vrow)[i];
            const int d0 = ch * 16 + i * 4;
            Lt[(d0 + 0) * 72 + r] = (_Float16)f.x;
            Lt[(d0 + 1) * 72 + r] = (_Float16)f.y;
            Lt[(d0 + 2) * 72 + r] = (_Float16)f.z;
            Lt[(d0 + 3) * 72 + r] = (_Float16)f.w;
        }
        __syncthreads();
        const int d  = t >> 2;               // dim row 0..63
        const int c2 = t & 3;                // 16-key chunk
        const half8_t w0 = *(const half8_t*)&Lt[d * 72 + c2 * 16];
        const half8_t w1 = *(const half8_t*)&Lt[d * 72 + c2 * 16 + 8];
        _Float16* orow = VT16 + ((size_t)bb * D_ + d) * L_ + kt * 64 + c2 * 16;
        *(half8_t*)orow = w0;
        *(half8_t*)(orow + 8) = w1;
    }
}

// -------------------------------------------------------------- main body --
__global__ __launch_bounds__(NT, 4) void attn_part(
    const float* __restrict__ Q,
    const _Float16* __restrict__ K16,
    const _Float16* __restrict__ VT16,
    float* __restrict__ Opart,
    float* __restrict__ lpart)
{
    // pool: main loop = per-wave P (4 x 32 x PS halves = 10240 B);
    // epilogue overlay = Ored[4][64][33] f32 (33792 B) + Lred[4][32] (512 B).
    __shared__ __align__(16) unsigned char pool[34304];

    const int t    = threadIdx.x;
    const int wave = t >> 6;
    const int lane = t & 63;
    const int quad = lane >> 4;
    const int l15  = lane & 15;

    const int b   = blockIdx.x & 7;            // batch <-> XCD affinity
    const int ks  = (blockIdx.x >> 3) & 1;     // key split half
    const int qbi = blockIdx.x >> 4;           // query block 0..63
    const int qb  = qbi * 32;
    const int key0 = ks * 1024 + wave * 256;

    _Float16* Pt   = (_Float16*)pool + wave * 32 * PS;
    float*    Ored = (float*)pool;
    float*    Lred = (float*)(pool + 33792);

    const _Float16* Kb = K16 + (size_t)b * L_ * D_;
    const _Float16* Vb = VT16 + (size_t)b * D_ * L_;

    // ---- Q A-frags from fp32, pre-scaled by 0.125*log2(e) ----
    half8_t aq[2][2];
    #pragma unroll
    for (int qs = 0; qs < 2; ++qs) {
        const float* qp = Q + ((size_t)b * L_ + qb + qs * 16 + l15) * D_ + quad * 8;
        #pragma unroll
        for (int c = 0; c < 2; ++c) {
            const float4 f0 = *(const float4*)(qp + c * 32);
            const float4 f1 = *(const float4*)(qp + c * 32 + 4);
            aq[qs][c][0] = (_Float16)(f0.x * SCALE_LOG2E);
            aq[qs][c][1] = (_Float16)(f0.y * SCALE_LOG2E);
            aq[qs][c][2] = (_Float16)(f0.z * SCALE_LOG2E);
            aq[qs][c][3] = (_Float16)(f0.w * SCALE_LOG2E);
            aq[qs][c][4] = (_Float16)(f1.x * SCALE_LOG2E);
            aq[qs][c][5] = (_Float16)(f1.y * SCALE_LOG2E);
            aq[qs][c][6] = (_Float16)(f1.z * SCALE_LOG2E);
            aq[qs][c][7] = (_Float16)(f1.w * SCALE_LOG2E);
        }
    }

    f32x4 ofr[2][4];
    #pragma unroll
    for (int qs = 0; qs < 2; ++qs)
        #pragma unroll
        for (int d = 0; d < 4; ++d)
            ofr[qs][d] = (f32x4){0.f, 0.f, 0.f, 0.f};
    float lacc[2][4] = {{0.f, 0.f, 0.f, 0.f}, {0.f, 0.f, 0.f, 0.f}};

    for (int kt = 0; kt < 256 / TK; ++kt) {
        const int kbase = key0 + kt * TK;

        // ---- all global loads for this tile issued together ----
        half8_t bk[2][2];
        #pragma unroll
        for (int s = 0; s < 2; ++s)
            #pragma unroll
            for (int c = 0; c < 2; ++c)
                bk[s][c] = *(const half8_t*)&Kb[(size_t)(kbase + s * 16 + l15) * D_ + c * 32 + quad * 8];
        half8_t bv[4];
        #pragma unroll
        for (int d = 0; d < 4; ++d)
            bv[d] = *(const half8_t*)&Vb[(size_t)(d * 16 + l15) * L_ + kbase + quad * 8];

        // ---- QK^T ----
        f32x4 sc[2][2];
        #pragma unroll
        for (int qs = 0; qs < 2; ++qs)
            #pragma unroll
            for (int s = 0; s < 2; ++s) {
                f32x4 acc = (f32x4){0.f, 0.f, 0.f, 0.f};
                acc = __builtin_amdgcn_mfma_f32_16x16x32_f16(aq[qs][0], bk[s][0], acc, 0, 0, 0);
                acc = __builtin_amdgcn_mfma_f32_16x16x32_f16(aq[qs][1], bk[s][1], acc, 0, 0, 0);
                sc[qs][s] = acc;
            }

        // ---- softmax: p = 2^sc (scale folded into Q) -> P in LDS ----
        #pragma unroll
        for (int qs = 0; qs < 2; ++qs)
            #pragma unroll
            for (int s = 0; s < 2; ++s)
                #pragma unroll
                for (int r = 0; r < 4; ++r) {
                    const float p = __builtin_exp2f(sc[qs][s][r]);
                    lacc[qs][r] += p;
                    Pt[(qs * 16 + quad * 4 + r) * PS + s * 16 + l15] = (_Float16)p;
                }

        __builtin_amdgcn_wave_barrier();   // P writes before P reads

        half8_t ap[2];
        #pragma unroll
        for (int qs = 0; qs < 2; ++qs)
            ap[qs] = *(const half8_t*)&Pt[(qs * 16 + l15) * PS + quad * 8];

        #pragma unroll
        for (int qs = 0; qs < 2; ++qs)
            #pragma unroll
            for (int d = 0; d < 4; ++d)
                ofr[qs][d] = __builtin_amdgcn_mfma_f32_16x16x32_f16(ap[qs], bv[d], ofr[qs][d], 0, 0, 0);

        __builtin_amdgcn_wave_barrier();   // P reads before next tile's writes
    }

    // ---- reduce l across each 16-lane group ----
    #pragma unroll
    for (int qs = 0; qs < 2; ++qs)
        #pragma unroll
        for (int r = 0; r < 4; ++r) {
            float v = lacc[qs][r];
            v += __shfl_xor(v, 1, 64);
            v += __shfl_xor(v, 2, 64);
            v += __shfl_xor(v, 4, 64);
            v += __shfl_xor(v, 8, 64);
            lacc[qs][r] = v;
        }

    __syncthreads();   // P region dead; safe to overlay Ored

    #pragma unroll
    for (int qs = 0; qs < 2; ++qs)
        #pragma unroll
        for (int d = 0; d < 4; ++d)
            #pragma unroll
            for (int r = 0; r < 4; ++r)
                Ored[(wave * 64 + lane) * 33 + qs * 16 + d * 4 + r] = ofr[qs][d][r];
    if (l15 == 0) {
        #pragma unroll
        for (int qs = 0; qs < 2; ++qs)
            #pragma unroll
            for (int r = 0; r < 4; ++r)
                Lred[wave * 32 + qs * 16 + quad * 4 + r] = lacc[qs][r];
    }
    __syncthreads();

    // ---- write un-normalized partial (block sums 4 waves; no normalize) ----
    const size_t pidx  = (size_t)(b * 64 + qbi) * 2 + ks;
    float* ob = Opart + pidx * 2048;
    float* lb = lpart + pidx * 32;
    #pragma unroll
    for (int qs = 0; qs < 2; ++qs)
        #pragma unroll
        for (int r = 0; r < 4; ++r) {
            float osum = 0.f;
            #pragma unroll
            for (int w2 = 0; w2 < 4; ++w2)
                osum += Ored[(w2 * 64 + lane) * 33 + qs * 16 + wave * 4 + r];
            const int row = qs * 16 + quad * 4 + r;
            ob[row * 64 + wave * 16 + l15] = osum;
            if (wave == 0 && l15 == 0)
                lb[row] = Lred[row] + Lred[32 + row] + Lred[64 + row] + Lred[96 + row];
        }
}

// ---------------------------------------------------------------- combine --
__global__ __launch_bounds__(NT) void combine(
    const float* __restrict__ Opart, const float* __restrict__ lpart,
    float* __restrict__ O)
{
    const int blk = blockIdx.x;       // 0..511 = b*64 + qbi
    const int t = threadIdx.x;
    const float4* p0 = (const float4*)(Opart + (size_t)blk * 2 * 2048);
    const float4* p1 = p0 + 512;
    const float* l0 = lpart + (size_t)blk * 2 * 32;
    const float* l1 = l0 + 32;
    float4* out = (float4*)(O + (size_t)blk * 2048);
    #pragma unroll
    for (int i = 0; i < 2; ++i) {
        const int idx = i * NT + t;
        const int q = idx >> 4;
        const float inv = 1.0f / (l0[q] + l1[q]);
        const float4 a = p0[idx];
        const float4 b = p1[idx];
        float4 r;
        r.x = (a.x + b.x) * inv; r.y = (a.y + b.y) * inv;
        r.z = (a.z + b.z) * inv; r.w = (a.w + b.w) * inv;
        out[idx] = r;
    }
}

// ------------------------------------------------- fallback (R3, no ws) --
#define KS 72
__global__ __launch_bounds__(NT) void attn_mfma_f16(
    const float* __restrict__ Q, const float* __restrict__ K,
    const float* __restrict__ V, float* __restrict__ O)
{
    __shared__ __align__(16) _Float16 Kt[64 * KS];
    __shared__ __align__(16) _Float16 Vt[D_ * KS];
    __shared__ __align__(16) _Float16 Pt[4][16 * KS];

    const int t = threadIdx.x;
    const int wave = t >> 6, lane = t & 63, quad = lane >> 4, l15 = lane & 15;
    const int bpb = L_ / 64;
    const int b = blockIdx.x / bpb;
    const int qb = (blockIdx.x % bpb) * 64 + wave * 16;
    const size_t boff = (size_t)b * L_ * D_;

    half8_t aq[2];
    {
        const float* qp = Q + boff + (size_t)(qb + l15) * D_ + quad * 8;
        #pragma unroll
        for (int c = 0; c < 2; ++c) {
            const float4* p4 = (const float4*)(qp + c * 32);
            const float4 f0 = p4[0], f1 = p4[1];
            aq[c][0] = (_Float16)f0.x; aq[c][1] = (_Float16)f0.y;
            aq[c][2] = (_Float16)f0.z; aq[c][3] = (_Float16)f0.w;
            aq[c][4] = (_Float16)f1.x; aq[c][5] = (_Float16)f1.y;
            aq[c][6] = (_Float16)f1.z; aq[c][7] = (_Float16)f1.w;
        }
    }
    f32x4 ofr[4];
    #pragma unroll
    for (int d = 0; d < 4; ++d) ofr[d] = (f32x4){0.f, 0.f, 0.f, 0.f};
    float lacc[4] = {0.f, 0.f, 0.f, 0.f};
    const int skey = t & 63, sdg = t >> 6;
    _Float16* Pw = &Pt[wave][0];

    for (int kt = 0; kt < L_ / 64; ++kt) {
        __syncthreads();
        {
            const float4* kg4 = (const float4*)(K + boff + (size_t)(kt * 64 + skey) * D_ + sdg * 16);
            const float4 f0 = kg4[0], f1 = kg4[1], f2 = kg4[2], f3 = kg4[3];
            half8_t w0, w1;
            w0[0] = (_Float16)f0.x; w0[1] = (_Float16)f0.y;
            w0[2] = (_Float16)f0.z; w0[3] = (_Float16)f0.w;
            w0[4] = (_Float16)f1.x; w0[5] = (_Float16)f1.y;
            w0[6] = (_Float16)f1.z; w0[7] = (_Float16)f1.w;
            w1[0] = (_Float16)f2.x; w1[1] = (_Float16)f2.y;
            w1[2] = (_Float16)f2.z; w1[3] = (_Float16)f2.w;
            w1[4] = (_Float16)f3.x; w1[5] = (_Float16)f3.y;
            w1[6] = (_Float16)f3.z; w1[7] = (_Float16)f3.w;
            *(half8_t*)&Kt[skey * KS + sdg * 16] = w0;
            *(half8_t*)&Kt[skey * KS + sdg * 16 + 8] = w1;
        }
        {
            const float4* vg4 = (const float4*)(V + boff + (size_t)(kt * 64 + skey) * D_ + sdg * 16);
            #pragma unroll
            for (int i = 0; i < 4; ++i) {
                const float4 f = vg4[i];
                const int d0 = sdg * 16 + i * 4;
                Vt[(d0 + 0) * KS + skey] = (_Float16)f.x;
                Vt[(d0 + 1) * KS + skey] = (_Float16)f.y;
                Vt[(d0 + 2) * KS + skey] = (_Float16)f.z;
                Vt[(d0 + 3) * KS + skey] = (_Float16)f.w;
            }
        }
        __syncthreads();
        #pragma unroll
        for (int s = 0; s < 4; ++s) {
            const half8_t bk0 = *(const half8_t*)&Kt[(s * 16 + l15) * KS + quad * 8];
            const half8_t bk1 = *(const half8_t*)&Kt[(s * 16 + l15) * KS + 32 + quad * 8];
            f32x4 sc = (f32x4){0.f, 0.f, 0.f, 0.f};
            sc = __builtin_amdgcn_mfma_f32_16x16x32_f16(aq[0], bk0, sc, 0, 0, 0);
            sc = __builtin_amdgcn_mfma_f32_16x16x32_f16(aq[1], bk1, sc, 0, 0, 0);
            #pragma unroll
            for (int r = 0; r < 4; ++r) {
                const float p = __expf(sc[r] * 0.125f);
                lacc[r] += p;
                Pw[(quad * 4 + r) * KS + s * 16 + l15] = (_Float16)p;
            }
        }
        __syncthreads();
        #pragma unroll
        for (int c = 0; c < 2; ++c) {
            const half8_t ap = *(const half8_t*)&Pw[l15 * KS + c * 32 + quad * 8];
            #pragma unroll
            for (int d = 0; d < 4; ++d) {
                const half8_t bv = *(const half8_t*)&Vt[(d * 16 + l15) * KS + c * 32 + quad * 8];
                ofr[d] = __builtin_amdgcn_mfma_f32_16x16x32_f16(ap, bv, ofr[d], 0, 0, 0);
            }
        }
    }
    #pragma unroll
    for (int r = 0; r < 4; ++r) {
        float v = lacc[r];
        v += __shfl_xor(v, 1, 64);
        v += __shfl_xor(v, 2, 64);
        v += __shfl_xor(v, 4, 64);
        v += __shfl_xor(v, 8, 64);
        lacc[r] = v;
    }
    #pragma unroll
    for (int r = 0; r < 4; ++r) {
        const float inv = 1.0f / lacc[r];
        float* orow = O + boff + (size_t)(qb + quad * 4 + r) * D_ + l15;
        #pragma unroll
        for (int d = 0; d < 4; ++d) orow[d * 16] = ofr[d][r] * inv;
    }
}

extern "C" void kernel_launch(void* const* d_in, const int* in_sizes, int n_in,
                              void* d_out, int out_size, void* d_ws, size_t ws_size,
                              hipStream_t stream) {
    const float* Q = (const float*)d_in[0];
    const float* K = (const float*)d_in[1];
    const float* V = (const float*)d_in[2];
    float* O = (float*)d_out;

    if (ws_size >= (size_t)16 * 1024 * 1024) {
        _Float16* K16  = (_Float16*)d_ws;                              // 2 MB
        _Float16* VT16 = K16 + 1048576;                                // 2 MB
        float* Opart = (float*)((char*)d_ws + 4 * 1024 * 1024);        // 8 MB
        float* lpart = (float*)((char*)d_ws + 12 * 1024 * 1024);       // 128 KB
        prepass<<<768, NT, 0, stream>>>(K, V, K16, VT16);
        attn_part<<<1024, NT, 0, stream>>>(Q, K16, VT16, Opart, lpart);
        combine<<<512, NT, 0, stream>>>(Opart, lpart, O);
    } else {
        attn_mfma_f16<<<256, NT, 0, stream>>>(Q, K, V, O);
    }
}

// Round 6
// 98.347 us; speedup vs baseline: 1.0816x; 1.0816x over previous
//
#include <hip/hip_runtime.h>

// ScaledDotProductAttention B=8, L=2048, D=64, fp32 in/out.
//
// Two-launch scheme (ws >= 8 MB):
//  1) prepass: K -> fp16 copy (K16), V -> fp16 transposed (VT16) in d_ws.
//  2) attn_sw: grid 512 (8 batch x 64 qblocks of 32 queries), 4 waves/block,
//     wave w owns keys [w*512, w*512+512) in 16 tiles of 32.
//     SOFTWARE-PIPELINED K-loop:
//       stage t: [prefetch bk(t+1)] -> QK(t) -> exp -> write P[t&1]
//                -> read ap from P[(t-1)&1] -> PV(t-1) -> [prefetch bv(t+1)]
//     bk/bv double-buffered in registers; P double-buffered in two DISTINCT
//     __shared__ arrays (P0s/P1s) so the compiler's fine-grained lgkmcnt
//     never drains the just-issued writes: the exp->write->read chain of a
//     tile is covered by a full stage of independent MFMA/VALU work.
//     Q loaded fp32, pre-scaled by 0.125*log2(e) -> softmax is one v_exp2.
//     Cross-wave (O,l) combine in LDS epilogue, normalized store.
// Fallback: proven R3 kernel if ws too small.

#define B_ 8
#define L_ 2048
#define D_ 64
#define NT 256
#define PS 40              // P row stride in halves (80 B, rows 16B-aligned)
#define TK 32              // keys per tile
#define NTILE 16           // 512 keys per wave

typedef _Float16 half8_t __attribute__((ext_vector_type(8)));
typedef float f32x4 __attribute__((ext_vector_type(4)));

#define SCALE_LOG2E 0.1803368801111244f   // 0.125 * log2(e)

// ---------------------------------------------------------------- prepass --
// blocks 0..511: K cast; 512..767: V transpose.
__global__ __launch_bounds__(NT) void prepass(
    const float* __restrict__ K, const float* __restrict__ V,
    _Float16* __restrict__ K16, _Float16* __restrict__ VT16)
{
    const int blk = blockIdx.x;
    const int t = threadIdx.x;
    if (blk < 512) {
        const int i = blk * NT + t;                  // half8 index, 131072 total
        const float4* s4 = (const float4*)K;
        const float4 a = s4[2 * i], b = s4[2 * i + 1];
        half8_t w;
        w[0] = (_Float16)a.x; w[1] = (_Float16)a.y;
        w[2] = (_Float16)a.z; w[3] = (_Float16)a.w;
        w[4] = (_Float16)b.x; w[5] = (_Float16)b.y;
        w[6] = (_Float16)b.z; w[7] = (_Float16)b.w;
        ((half8_t*)K16)[i] = w;
    } else {
        __shared__ __align__(16) _Float16 Lt[64 * 72];   // [dim][key] tile
        const int vblk = blk - 512;
        const int bb = vblk >> 5;            // batch
        const int kt = vblk & 31;            // 64-key tile
        const int r  = t >> 2;               // key row 0..63
        const int ch = t & 3;                // 16-dim chunk
        const float* vrow = V + ((size_t)bb * L_ + kt * 64 + r) * D_ + ch * 16;
        #pragma unroll
        for (int i = 0; i < 4; ++i) {
            const float4 f = ((const float4*)vrow)[i];
            const int d0 = ch * 16 + i * 4;
            Lt[(d0 + 0) * 72 + r] = (_Float16)f.x;
            Lt[(d0 + 1) * 72 + r] = (_Float16)f.y;
            Lt[(d0 + 2) * 72 + r] = (_Float16)f.z;
            Lt[(d0 + 3) * 72 + r] = (_Float16)f.w;
        }
        __syncthreads();
        const int d  = t >> 2;               // dim row 0..63
        const int c2 = t & 3;                // 16-key chunk
        const half8_t w0 = *(const half8_t*)&Lt[d * 72 + c2 * 16];
        const half8_t w1 = *(const half8_t*)&Lt[d * 72 + c2 * 16 + 8];
        _Float16* orow = VT16 + ((size_t)bb * D_ + d) * L_ + kt * 64 + c2 * 16;
        *(half8_t*)orow = w0;
        *(half8_t*)(orow + 8) = w1;
    }
}

// -------------------------------------------------------------- main body --

// One pipeline stage: prefetch bk(TP+1) -> QK(TP) -> exp -> write PW ->
// read ap from PR -> PV(TP-1) with BVP -> prefetch bv(TP+1) into BVP.
#define STAGE(TP, PW, PR, BKC, BKN, BVP, DO_PF)                                 \
    {                                                                           \
        const int kb_pf = key0 + ((TP) + 1) * TK;                               \
        if (DO_PF) {                                                            \
            _Pragma("unroll") for (int s = 0; s < 2; ++s)                       \
            _Pragma("unroll") for (int c = 0; c < 2; ++c)                       \
                BKN[s][c] = *(const half8_t*)&Kb[(size_t)(kb_pf + s * 16 + l15) * D_ + c * 32 + quad * 8]; \
        }                                                                       \
        f32x4 sc[2][2];                                                         \
        _Pragma("unroll") for (int qs = 0; qs < 2; ++qs)                        \
        _Pragma("unroll") for (int s = 0; s < 2; ++s) {                         \
            f32x4 acc = (f32x4){0.f, 0.f, 0.f, 0.f};                            \
            acc = __builtin_amdgcn_mfma_f32_16x16x32_f16(aq[qs][0], BKC[s][0], acc, 0, 0, 0); \
            acc = __builtin_amdgcn_mfma_f32_16x16x32_f16(aq[qs][1], BKC[s][1], acc, 0, 0, 0); \
            sc[qs][s] = acc;                                                    \
        }                                                                       \
        _Pragma("unroll") for (int qs = 0; qs < 2; ++qs)                        \
        _Pragma("unroll") for (int s = 0; s < 2; ++s)                           \
        _Pragma("unroll") for (int r = 0; r < 4; ++r) {                         \
            const float p = __builtin_exp2f(sc[qs][s][r]);                      \
            lacc[qs][r] += p;                                                   \
            PW[(qs * 16 + quad * 4 + r) * PS + s * 16 + l15] = (_Float16)p;     \
        }                                                                       \
        half8_t ap[2];                                                          \
        _Pragma("unroll") for (int qs = 0; qs < 2; ++qs)                        \
            ap[qs] = *(const half8_t*)&PR[(qs * 16 + l15) * PS + quad * 8];     \
        _Pragma("unroll") for (int qs = 0; qs < 2; ++qs)                        \
        _Pragma("unroll") for (int d = 0; d < 4; ++d)                           \
            ofr[qs][d] = __builtin_amdgcn_mfma_f32_16x16x32_f16(ap[qs], BVP[d], ofr[qs][d], 0, 0, 0); \
        if (DO_PF) {                                                            \
            _Pragma("unroll") for (int d = 0; d < 4; ++d)                       \
                BVP[d] = *(const half8_t*)&Vb[(size_t)(d * 16 + l15) * L_ + kb_pf + quad * 8]; \
        }                                                                       \
    }

__global__ __launch_bounds__(NT) void attn_sw(
    const float* __restrict__ Q,
    const _Float16* __restrict__ K16,
    const _Float16* __restrict__ VT16,
    float* __restrict__ O)
{
    __shared__ __align__(16) _Float16 P0s[4][32 * PS];   // 10240 B
    __shared__ __align__(16) _Float16 P1s[4][32 * PS];   // 10240 B
    __shared__ float Ored[256 * 33];                     // 33792 B
    __shared__ float Lred[128];                          // 512 B

    const int t    = threadIdx.x;
    const int wave = t >> 6;
    const int lane = t & 63;
    const int quad = lane >> 4;
    const int l15  = lane & 15;

    const int b   = blockIdx.x & 7;            // batch <-> XCD affinity
    const int qbi = blockIdx.x >> 3;           // query block 0..63
    const int qb  = qbi * 32;
    const int key0 = wave * (TK * NTILE);      // wave's 512-key range

    _Float16* P0w = P0s[wave];
    _Float16* P1w = P1s[wave];

    const _Float16* Kb = K16 + (size_t)b * L_ * D_;
    const _Float16* Vb = VT16 + (size_t)b * D_ * L_;

    // ---- Q A-frags from fp32, pre-scaled by 0.125*log2(e) ----
    half8_t aq[2][2];
    #pragma unroll
    for (int qs = 0; qs < 2; ++qs) {
        const float* qp = Q + ((size_t)b * L_ + qb + qs * 16 + l15) * D_ + quad * 8;
        #pragma unroll
        for (int c = 0; c < 2; ++c) {
            const float4 f0 = *(const float4*)(qp + c * 32);
            const float4 f1 = *(const float4*)(qp + c * 32 + 4);
            aq[qs][c][0] = (_Float16)(f0.x * SCALE_LOG2E);
            aq[qs][c][1] = (_Float16)(f0.y * SCALE_LOG2E);
            aq[qs][c][2] = (_Float16)(f0.z * SCALE_LOG2E);
            aq[qs][c][3] = (_Float16)(f0.w * SCALE_LOG2E);
            aq[qs][c][4] = (_Float16)(f1.x * SCALE_LOG2E);
            aq[qs][c][5] = (_Float16)(f1.y * SCALE_LOG2E);
            aq[qs][c][6] = (_Float16)(f1.z * SCALE_LOG2E);
            aq[qs][c][7] = (_Float16)(f1.w * SCALE_LOG2E);
        }
    }

    f32x4 ofr[2][4];
    #pragma unroll
    for (int qs = 0; qs < 2; ++qs)
        #pragma unroll
        for (int d = 0; d < 4; ++d)
            ofr[qs][d] = (f32x4){0.f, 0.f, 0.f, 0.f};
    float lacc[2][4] = {{0.f, 0.f, 0.f, 0.f}, {0.f, 0.f, 0.f, 0.f}};

    // ---- prologue: load tiles 0 and 1; QK(0) -> P0 ----
    half8_t bk0[2][2], bk1[2][2], bv0[4], bv1[4];
    #pragma unroll
    for (int s = 0; s < 2; ++s)
        #pragma unroll
        for (int c = 0; c < 2; ++c) {
            bk0[s][c] = *(const half8_t*)&Kb[(size_t)(key0 + s * 16 + l15) * D_ + c * 32 + quad * 8];
            bk1[s][c] = *(const half8_t*)&Kb[(size_t)(key0 + TK + s * 16 + l15) * D_ + c * 32 + quad * 8];
        }
    #pragma unroll
    for (int d = 0; d < 4; ++d) {
        bv0[d] = *(const half8_t*)&Vb[(size_t)(d * 16 + l15) * L_ + key0 + quad * 8];
        bv1[d] = *(const half8_t*)&Vb[(size_t)(d * 16 + l15) * L_ + key0 + TK + quad * 8];
    }
    {
        f32x4 sc[2][2];
        #pragma unroll
        for (int qs = 0; qs < 2; ++qs)
            #pragma unroll
            for (int s = 0; s < 2; ++s) {
                f32x4 acc = (f32x4){0.f, 0.f, 0.f, 0.f};
                acc = __builtin_amdgcn_mfma_f32_16x16x32_f16(aq[qs][0], bk0[s][0], acc, 0, 0, 0);
                acc = __builtin_amdgcn_mfma_f32_16x16x32_f16(aq[qs][1], bk0[s][1], acc, 0, 0, 0);
                sc[qs][s] = acc;
            }
        #pragma unroll
        for (int qs = 0; qs < 2; ++qs)
            #pragma unroll
            for (int s = 0; s < 2; ++s)
                #pragma unroll
                for (int r = 0; r < 4; ++r) {
                    const float p = __builtin_exp2f(sc[qs][s][r]);
                    lacc[qs][r] += p;
                    P0w[(qs * 16 + quad * 4 + r) * PS + s * 16 + l15] = (_Float16)p;
                }
    }

    // ---- pipelined stages: QK(t) & PV(t-1), t = 1..15 ----
    for (int tp = 1; tp <= 13; tp += 2) {
        STAGE(tp,     P1w, P0w, bk1, bk0, bv0, true)   // odd t
        STAGE(tp + 1, P0w, P1w, bk0, bk1, bv1, true)   // even t
    }
    STAGE(15, P1w, P0w, bk1, bk0, bv0, false)

    // ---- tail: PV(15) (P in P1, bv1 holds tile 15) ----
    {
        half8_t ap[2];
        #pragma unroll
        for (int qs = 0; qs < 2; ++qs)
            ap[qs] = *(const half8_t*)&P1w[(qs * 16 + l15) * PS + quad * 8];
        #pragma unroll
        for (int qs = 0; qs < 2; ++qs)
            #pragma unroll
            for (int d = 0; d < 4; ++d)
                ofr[qs][d] = __builtin_amdgcn_mfma_f32_16x16x32_f16(ap[qs], bv1[d], ofr[qs][d], 0, 0, 0);
    }

    // ---- reduce l across each 16-lane group ----
    #pragma unroll
    for (int qs = 0; qs < 2; ++qs)
        #pragma unroll
        for (int r = 0; r < 4; ++r) {
            float v = lacc[qs][r];
            v += __shfl_xor(v, 1, 64);
            v += __shfl_xor(v, 2, 64);
            v += __shfl_xor(v, 4, 64);
            v += __shfl_xor(v, 8, 64);
            lacc[qs][r] = v;
        }

    // ---- cross-wave combine (waves own disjoint keys) ----
    #pragma unroll
    for (int qs = 0; qs < 2; ++qs)
        #pragma unroll
        for (int d = 0; d < 4; ++d)
            #pragma unroll
            for (int r = 0; r < 4; ++r)
                Ored[(wave * 64 + lane) * 33 + qs * 16 + d * 4 + r] = ofr[qs][d][r];
    if (l15 == 0) {
        #pragma unroll
        for (int qs = 0; qs < 2; ++qs)
            #pragma unroll
            for (int r = 0; r < 4; ++r)
                Lred[wave * 32 + qs * 16 + quad * 4 + r] = lacc[qs][r];
    }
    __syncthreads();

    #pragma unroll
    for (int qs = 0; qs < 2; ++qs)
        #pragma unroll
        for (int r = 0; r < 4; ++r) {
            float osum = 0.f;
            #pragma unroll
            for (int w2 = 0; w2 < 4; ++w2)
                osum += Ored[(w2 * 64 + lane) * 33 + qs * 16 + wave * 4 + r];
            const int row = qs * 16 + quad * 4 + r;
            const float lt = Lred[row] + Lred[32 + row] + Lred[64 + row] + Lred[96 + row];
            O[((size_t)b * L_ + qb + row) * D_ + wave * 16 + l15] = osum / lt;
        }
}

// ------------------------------------------------- fallback (R3, no ws) --
#define KS 72
__global__ __launch_bounds__(NT) void attn_mfma_f16(
    const float* __restrict__ Q, const float* __restrict__ K,
    const float* __restrict__ V, float* __restrict__ O)
{
    __shared__ __align__(16) _Float16 Kt[64 * KS];
    __shared__ __align__(16) _Float16 Vt[D_ * KS];
    __shared__ __align__(16) _Float16 Pt[4][16 * KS];

    const int t = threadIdx.x;
    const int wave = t >> 6, lane = t & 63, quad = lane >> 4, l15 = lane & 15;
    const int bpb = L_ / 64;
    const int b = blockIdx.x / bpb;
    const int qb = (blockIdx.x % bpb) * 64 + wave * 16;
    const size_t boff = (size_t)b * L_ * D_;

    half8_t aq[2];
    {
        const float* qp = Q + boff + (size_t)(qb + l15) * D_ + quad * 8;
        #pragma unroll
        for (int c = 0; c < 2; ++c) {
            const float4* p4 = (const float4*)(qp + c * 32);
            const float4 f0 = p4[0], f1 = p4[1];
            aq[c][0] = (_Float16)f0.x; aq[c][1] = (_Float16)f0.y;
            aq[c][2] = (_Float16)f0.z; aq[c][3] = (_Float16)f0.w;
            aq[c][4] = (_Float16)f1.x; aq[c][5] = (_Float16)f1.y;
            aq[c][6] = (_Float16)f1.z; aq[c][7] = (_Float16)f1.w;
        }
    }
    f32x4 ofr[4];
    #pragma unroll
    for (int d = 0; d < 4; ++d) ofr[d] = (f32x4){0.f, 0.f, 0.f, 0.f};
    float lacc[4] = {0.f, 0.f, 0.f, 0.f};
    const int skey = t & 63, sdg = t >> 6;
    _Float16* Pw = &Pt[wave][0];

    for (int kt = 0; kt < L_ / 64; ++kt) {
        __syncthreads();
        {
            const float4* kg4 = (const float4*)(K + boff + (size_t)(kt * 64 + skey) * D_ + sdg * 16);
            const float4 f0 = kg4[0], f1 = kg4[1], f2 = kg4[2], f3 = kg4[3];
            half8_t w0, w1;
            w0[0] = (_Float16)f0.x; w0[1] = (_Float16)f0.y;
            w0[2] = (_Float16)f0.z; w0[3] = (_Float16)f0.w;
            w0[4] = (_Float16)f1.x; w0[5] = (_Float16)f1.y;
            w0[6] = (_Float16)f1.z; w0[7] = (_Float16)f1.w;
            w1[0] = (_Float16)f2.x; w1[1] = (_Float16)f2.y;
            w1[2] = (_Float16)f2.z; w1[3] = (_Float16)f2.w;
            w1[4] = (_Float16)f3.x; w1[5] = (_Float16)f3.y;
            w1[6] = (_Float16)f3.z; w1[7] = (_Float16)f3.w;
            *(half8_t*)&Kt[skey * KS + sdg * 16] = w0;
            *(half8_t*)&Kt[skey * KS + sdg * 16 + 8] = w1;
        }
        {
            const float4* vg4 = (const float4*)(V + boff + (size_t)(kt * 64 + skey) * D_ + sdg * 16);
            #pragma unroll
            for (int i = 0; i < 4; ++i) {
                const float4 f = vg4[i];
                const int d0 = sdg * 16 + i * 4;
                Vt[(d0 + 0) * KS + skey] = (_Float16)f.x;
                Vt[(d0 + 1) * KS + skey] = (_Float16)f.y;
                Vt[(d0 + 2) * KS + skey] = (_Float16)f.z;
                Vt[(d0 + 3) * KS + skey] = (_Float16)f.w;
            }
        }
        __syncthreads();
        #pragma unroll
        for (int s = 0; s < 4; ++s) {
            const half8_t bk0 = *(const half8_t*)&Kt[(s * 16 + l15) * KS + quad * 8];
            const half8_t bk1 = *(const half8_t*)&Kt[(s * 16 + l15) * KS + 32 + quad * 8];
            f32x4 sc = (f32x4){0.f, 0.f, 0.f, 0.f};
            sc = __builtin_amdgcn_mfma_f32_16x16x32_f16(aq[0], bk0, sc, 0, 0, 0);
            sc = __builtin_amdgcn_mfma_f32_16x16x32_f16(aq[1], bk1, sc, 0, 0, 0);
            #pragma unroll
            for (int r = 0; r < 4; ++r) {
                const float p = __expf(sc[r] * 0.125f);
                lacc[r] += p;
                Pw[(quad * 4 + r) * KS + s * 16 + l15] = (_Float16)p;
            }
        }
        __syncthreads();
        #pragma unroll
        for (int c = 0; c < 2; ++c) {
            const half8_t ap = *(const half8_t*)&Pw[l15 * KS + c * 32 + quad * 8];
            #pragma unroll
            for (int d = 0; d < 4; ++d) {
                const half8_t bv = *(const half8_t*)&Vt[(d * 16 + l15) * KS + c * 32 + quad * 8];
                ofr[d] = __builtin_amdgcn_mfma_f32_16x16x32_f16(ap, bv, ofr[d], 0, 0, 0);
            }
        }
    }
    #pragma unroll
    for (int r = 0; r < 4; ++r) {
        float v = lacc[r];
        v += __shfl_xor(v, 1, 64);
        v += __shfl_xor(v, 2, 64);
        v += __shfl_xor(v, 4, 64);
        v += __shfl_xor(v, 8, 64);
        lacc[r] = v;
    }
    #pragma unroll
    for (int r = 0; r < 4; ++r) {
        const float inv = 1.0f / lacc[r];
        float* orow = O + boff + (size_t)(qb + quad * 4 + r) * D_ + l15;
        #pragma unroll
        for (int d = 0; d < 4; ++d) orow[d * 16] = ofr[d][r] * inv;
    }
}

extern "C" void kernel_launch(void* const* d_in, const int* in_sizes, int n_in,
                              void* d_out, int out_size, void* d_ws, size_t ws_size,
                              hipStream_t stream) {
    const float* Q = (const float*)d_in[0];
    const float* K = (const float*)d_in[1];
    const float* V = (const float*)d_in[2];
    float* O = (float*)d_out;

    if (ws_size >= (size_t)8 * 1024 * 1024) {
        _Float16* K16  = (_Float16*)d_ws;                              // 2 MB
        _Float16* VT16 = K16 + (size_t)B_ * L_ * D_;                   // 2 MB
        prepass<<<768, NT, 0, stream>>>(K, V, K16, VT16);
        attn_sw<<<512, NT, 0, stream>>>(Q, K16, VT16, O);
    } else {
        attn_mfma_f16<<<256, NT, 0, stream>>>(Q, K, V, O);
    }
}